// Round 7
// baseline (400.479 us; speedup 1.0000x reference)
//
#include <hip/hip_runtime.h>
#include <math.h>

typedef _Float16 f16;
typedef f16 f16x8 __attribute__((ext_vector_type(8)));
typedef float f32x4 __attribute__((ext_vector_type(4)));

#define Bsz   16384
#define Tobs  8
#define PREDL 12
#define MR    32   // batch rows per main block

__device__ __forceinline__ float fast_sigm(float x) {
  float e = __builtin_amdgcn_exp2f(-1.44269504f * x);
  return __builtin_amdgcn_rcpf(1.f + e);
}
__device__ __forceinline__ float fast_tanh(float x) {
  float e = __builtin_amdgcn_exp2f(2.88539008f * x);  // e^(2x)
  return 1.f - 2.f * __builtin_amdgcn_rcpf(1.f + e);
}

// Abuf index: [buf(2)][kt(4)][mt(2)][lane(64)][j(8)] f16
#define AB(buf, kt, mt, lane, j) (((((buf)*4 + (kt))*2 + (mt))*64 + (lane))*8 + (j))
// cntA index: [t(8)][mt(2)][lane(64)][j(8)] f16
#define CA(t, mt, lane, j) ((((t)*2 + (mt))*64 + (lane))*8 + (j))

// Wfrag fragment slot: [ktw(9)][w(8)][nt(4)][lane(64)][j(8)] f16
// ktw 0..3: W_hh ; ktw 4: extras [cells(16)|wio(2)|0...] ; ktw 5..8: W_eff
#define WF(ktw, w, nt, lane) ((size_t)((((ktw)*8 + (w))*4 + (nt))*64 + (lane)) * 8)

// ---------------------------------------------------------------------------
// pack_all: one single-wave block per gate-row jo (512 blocks).
// cells[c] = sum_e table[c][e] * wspP[e],  wspP[e] = sum_m W_ih[jo][128+m]*W_sp[m][e]
// Emits Wfrag (W_hh | extras | W_eff = W_hh + wio (x) W_out) and the 3 biases.
// ---------------------------------------------------------------------------
__global__ __launch_bounds__(64) void pack_all(
    const float* __restrict__ W_ih, const float* __restrict__ W_hh,
    const float* __restrict__ W_in, const float* __restrict__ W_sp,
    const float* __restrict__ table,
    const float* __restrict__ b_in, const float* __restrict__ b_sp,
    const float* __restrict__ b_ih, const float* __restrict__ b_hh,
    const float* __restrict__ W_out, const float* __restrict__ b_out,
    f16* __restrict__ Wfrag, float* __restrict__ biasO,
    float* __restrict__ biasP, float* __restrict__ biasPE) {
  const int blk = blockIdx.x;            // 0..511
  const int nt = blk >> 7, w = (blk >> 4) & 7, l = blk & 15;
  const int jo = nt * 128 + w * 16 + l;  // original gate row
  const int m = threadIdx.x;             // 0..63
  __shared__ float st[256];              // hh[128] | eff[128]
  __shared__ float wspPS[32];
  __shared__ float cellsS[16];

  float a0 = W_ih[jo * 256 + m],        a1 = W_ih[jo * 256 + 64 + m];
  float s0 = W_ih[jo * 256 + 128 + m],  s1 = W_ih[jo * 256 + 192 + m];
  float hh0 = W_hh[jo * 128 + m],       hh1 = W_hh[jo * 128 + 64 + m];
  float bi0 = b_in[m], bi1 = b_in[64 + m];
  float bs0 = b_sp[m], bs1 = b_sp[64 + m];
  float wi00 = W_in[m * 2 + 0],        wi01 = W_in[m * 2 + 1];
  float wi10 = W_in[(64 + m) * 2 + 0], wi11 = W_in[(64 + m) * 2 + 1];
  float wo00 = W_out[m],       wo01 = W_out[64 + m];        // W_out[0][*]
  float wo10 = W_out[128 + m], wo11 = W_out[192 + m];       // W_out[1][*]

  auto red = [](float v) {
#pragma unroll
    for (int s = 1; s < 64; s <<= 1) v += __shfl_xor(v, s);
    return v;
  };

  // wspP[e] via butterfly reductions
#pragma unroll 4
  for (int e = 0; e < 32; ++e) {
    float wp = red(s0 * W_sp[m * 32 + e] + s1 * W_sp[(64 + m) * 32 + e]);
    if (m == e) wspPS[e] = wp;
  }
  __syncthreads();
  if (m < 16) {
    float s = 0.f;
#pragma unroll
    for (int e = 0; e < 32; ++e) s += table[m * 32 + e] * wspPS[e];
    cellsS[m] = s;
  }

  float wio0 = red(a0 * wi00 + a1 * wi10);
  float wio1 = red(a0 * wi01 + a1 * wi11);
  float dotA = red(a0 * bi0 + a1 * bi1);
  float dotS = red(s0 * bs0 + s1 * bs1);

  st[m] = hh0;
  st[64 + m] = hh1;
  st[128 + m] = hh0 + wio0 * wo00 + wio1 * wo10;
  st[192 + m] = hh1 + wio0 * wo01 + wio1 * wo11;
  __syncthreads();

  if (m < 32) {  // W_hh (which=0) and W_eff (which=1) fragment writes
    int u = m & 15, kt = u >> 2, q = u & 3;
    int which = m >> 4;
    int ktw = which ? kt + 5 : kt;
    f16x8 v;
#pragma unroll
    for (int j = 0; j < 8; ++j) v[j] = (f16)st[which * 128 + kt * 32 + q * 8 + j];
    *(f16x8*)(Wfrag + WF(ktw, w, nt, q * 16 + l)) = v;
  } else if (m < 36) {  // extras tile ktw=4, q = m-32
    int q = m - 32;
    f16x8 v;
#pragma unroll
    for (int j = 0; j < 8; ++j) {
      int kk = q * 8 + j;
      float x = (kk < 16) ? cellsS[kk] : (kk == 16 ? wio0 : (kk == 17 ? wio1 : 0.f));
      v[j] = (f16)x;
    }
    *(f16x8*)(Wfrag + WF(4, w, nt, q * 16 + l)) = v;
  } else if (m == 36) {
    int col = w * 64 + nt * 16 + l;  // permuted column index
    float base = b_ih[jo] + b_hh[jo];
    biasO[col] = base + dotA + dotS;
    float bp = base + dotA;
    biasP[col] = bp;
    biasPE[col] = bp + wio0 * b_out[0] + wio1 * b_out[1];
  }
}

// ---------------------------------------------------------------------------
// Main: 32 rows/block, 512 threads, __launch_bounds__(512,4) => <=128 regs,
// 2 blocks/CU. mt-split step halves acc pressure (16 AGPR) and overlaps
// half-0 epilogue VALU with half-1 MFMA issue. 1 barrier per step.
// ---------------------------------------------------------------------------
__global__ __launch_bounds__(512, 4) void social_lstm_main(
    const float* __restrict__ obs, const float* __restrict__ nb,
    const f16* __restrict__ Wfrag, const float* __restrict__ biasO,
    const float* __restrict__ biasP, const float* __restrict__ biasPE,
    const float* __restrict__ W_out, const float* __restrict__ b_out,
    float* __restrict__ out) {
  __shared__ __align__(16) f16 Abuf[2 * 4 * 2 * 64 * 8];  // 16 KB
  __shared__ __align__(16) f16 cntA[8 * 2 * 64 * 8];      // 16 KB obs A-panels

  const int tid = threadIdx.x;
  const int w = tid >> 6, ln = tid & 63;
  const int q = ln >> 4, l = ln & 15;
  const int b0 = blockIdx.x * MR;

  // zero Abuf buf0 + all of cntA (channels 18..31 must be 0.0, not garbage)
  for (int i = tid; i < 2048; i += 512) ((uint32_t*)Abuf)[i] = 0u;
  for (int i = tid; i < 4096; i += 512) ((uint32_t*)cntA)[i] = 0u;
  __syncthreads();

  // ---------------- fused social pooling (loads hoisted for MLP) ----------
  {
    const int g = ln >> 4, lg = ln & 15;
    const int r = w * 4 + g;  // local row 0..31
    float4 T[16];
#pragma unroll
    for (int jt = 0; jt < 4; ++jt) {
      const float4* tr =
          (const float4*)(nb + ((size_t)(b0 + r) * 64 + (lg + 16 * jt)) * 16);
#pragma unroll
      for (int u = 0; u < 4; ++u) T[jt * 4 + u] = tr[u];
    }
    const float4* orow = (const float4*)(obs + (size_t)(b0 + r) * 16);
    float4 O0 = orow[0], O1 = orow[1], O2 = orow[2], O3 = orow[3];
    float ox[8] = {O0.x, O0.z, O1.x, O1.z, O2.x, O2.z, O3.x, O3.z};
    float oy[8] = {O0.y, O0.w, O1.y, O1.w, O2.y, O2.w, O3.y, O3.w};
    unsigned long long h[8] = {0ull, 0ull, 0ull, 0ull, 0ull, 0ull, 0ull, 0ull};
#pragma unroll
    for (int jt = 0; jt < 4; ++jt) {
      float nx[8] = {T[jt*4+0].x, T[jt*4+0].z, T[jt*4+1].x, T[jt*4+1].z,
                     T[jt*4+2].x, T[jt*4+2].z, T[jt*4+3].x, T[jt*4+3].z};
      float ny[8] = {T[jt*4+0].y, T[jt*4+0].w, T[jt*4+1].y, T[jt*4+1].w,
                     T[jt*4+2].y, T[jt*4+2].w, T[jt*4+3].y, T[jt*4+3].w};
#pragma unroll
      for (int t = 0; t < 8; ++t) {
        float rx = nx[t] - ox[t], ry = ny[t] - oy[t];
        int ix = (int)floorf(rx + rx);
        int iy = (int)floorf(ry + ry);
        ix = min(max(ix, -2), 1);
        iy = min(max(iy, -2), 1);
        int flat = (ix + 2) * 4 + (iy + 2);   // 0..15, count per lane <= 4
        h[t] += 1ull << (flat * 4);           // 4-bit bins
      }
    }
    auto shx = [](unsigned long long x, int msk) {
      unsigned lo = __shfl_xor((unsigned)x, msk);
      unsigned hi = __shfl_xor((unsigned)(x >> 32), msk);
      return ((unsigned long long)hi << 32) | lo;
    };
#pragma unroll
    for (int t = 0; t < 8; ++t) {
      unsigned long long v = h[t];
      v += shx(v, 1);  // sums <= 8, still fits 4-bit bins
      unsigned long long e0 = v & 0x0F0F0F0F0F0F0F0Full;         // even bins, 8-bit
      unsigned long long e1 = (v >> 4) & 0x0F0F0F0F0F0F0F0Full;  // odd bins
      e0 += shx(e0, 2); e1 += shx(e1, 2);
      e0 += shx(e0, 4); e1 += shx(e1, 4);
      e0 += shx(e0, 8); e1 += shx(e1, 8);
      unsigned long long wsel = (lg & 1) ? e1 : e0;
      unsigned cnt = (unsigned)(wsel >> ((lg >> 1) * 8)) & 0xFFu;
      cntA[CA(t, r >> 4, (lg >> 3) * 16 + (r & 15), lg & 7)] = (f16)(float)cnt;
    }
    // xy channels 16,17
    int rr = tid >> 4, tt = (tid >> 1) & 7, comp = tid & 1;
    float xv = obs[(size_t)(b0 + rr) * 16 + tt * 2 + comp];
    cntA[CA(tt, rr >> 4, 2 * 16 + (rr & 15), comp)] = (f16)xv;
  }

  // persistent W_hh B fragments + extras (Bx dead after obs; regs recycle)
  f16x8 Bh[4][4];
#pragma unroll
  for (int kt = 0; kt < 4; ++kt)
#pragma unroll
    for (int nt = 0; nt < 4; ++nt)
      Bh[kt][nt] = *(const f16x8*)(Wfrag + WF(kt, w, nt, ln));
  f16x8 Bx[4];
#pragma unroll
  for (int nt = 0; nt < 4; ++nt) Bx[nt] = *(const f16x8*)(Wfrag + WF(4, w, nt, ln));

  float creg[8];
#pragma unroll
  for (int i = 0; i < 8; ++i) creg[i] = 0.f;

  float bOr[4];
#pragma unroll
  for (int g2 = 0; g2 < 4; ++g2) bOr[g2] = biasO[w * 64 + g2 * 16 + l];

  const int hc = w * 16 + l;
  const int aw_kt = hc >> 5, aw_quad = (hc >> 3) & 3, aw_j = l & 7;

  // One mt-half of a step: acc[4] only (16 regs), MFMA chain then epilogue.
  auto step_half = [&](int rb, int wb, int mt, const float* bq, bool ex, int t) {
    f32x4 a[4];
#pragma unroll
    for (int nt = 0; nt < 4; ++nt) a[nt] = (f32x4){bq[nt], bq[nt], bq[nt], bq[nt]};
    if (ex) {
      f16x8 Ax = *(const f16x8*)(&cntA[CA(t, mt, ln, 0)]);
#pragma unroll
      for (int nt = 0; nt < 4; ++nt)
        a[nt] = __builtin_amdgcn_mfma_f32_16x16x32_f16(Ax, Bx[nt], a[nt], 0, 0, 0);
    }
#pragma unroll
    for (int kt = 0; kt < 4; ++kt) {
      f16x8 Af = *(const f16x8*)(&Abuf[AB(rb, kt, mt, ln, 0)]);
#pragma unroll
      for (int nt = 0; nt < 4; ++nt)
        a[nt] = __builtin_amdgcn_mfma_f32_16x16x32_f16(Af, Bh[kt][nt], a[nt], 0, 0, 0);
    }
#pragma unroll
    for (int reg = 0; reg < 4; ++reg) {
      float p0 = a[0][reg], p1 = a[1][reg], p2 = a[2][reg], p3 = a[3][reg];
      float iv = fast_sigm(p0), fv = fast_sigm(p1);
      float gv = fast_tanh(p2), ov = fast_sigm(p3);
      int ci = mt * 4 + reg;
      float c2 = fv * creg[ci] + iv * gv;
      creg[ci] = c2;
      float hv = ov * fast_tanh(c2);
      Abuf[AB(wb, aw_kt, mt, (q * 4 + reg) + 16 * aw_quad, aw_j)] = (f16)hv;
    }
  };

  // ---------------- observation phase ----------------
#pragma unroll
  for (int t = 0; t < Tobs; ++t) {
    const int rb = t & 1, wb = rb ^ 1;
    __syncthreads();
    step_half(rb, wb, 0, bOr, true, t);
    step_half(rb, wb, 1, bOr, true, t);
  }

  // ---------------- prediction step 0 (prev disp = 0, plain W_hh) ----------
  {
    float bPr[4];
#pragma unroll
    for (int g2 = 0; g2 < 4; ++g2) bPr[g2] = biasP[w * 64 + g2 * 16 + l];
    const int rb = Tobs & 1, wb = rb ^ 1;  // rb=0, wb=1
    __syncthreads();
    step_half(rb, wb, 0, bPr, false, 0);
    step_half(rb, wb, 1, bPr, false, 0);
  }

  // swap to W_eff + biasPE; preload W_out dot registers for disp output
#pragma unroll
  for (int kt = 0; kt < 4; ++kt)
#pragma unroll
    for (int nt = 0; nt < 4; ++nt)
      Bh[kt][nt] = *(const f16x8*)(Wfrag + WF(kt + 5, w, nt, ln));
  float bEr[4];
#pragma unroll
  for (int g2 = 0; g2 < 4; ++g2) bEr[g2] = biasPE[w * 64 + g2 * 16 + l];

  const int d_oi = tid >> 3, d_seg = tid & 7;
  const int d_row = d_oi >> 1, d_jj = d_oi & 1;
  const int d_kt = d_seg >> 1, d_q0 = (d_seg & 1) * 2;
  float wor[16];
  {
    const float4* wp = (const float4*)(W_out + d_jj * 128 + d_seg * 16);
#pragma unroll
    for (int u = 0; u < 4; ++u) {
      float4 v = wp[u];
      wor[4 * u] = v.x; wor[4 * u + 1] = v.y; wor[4 * u + 2] = v.z; wor[4 * u + 3] = v.w;
    }
  }
  const float d_bo = b_out[d_jj];

  auto disp_out = [&](int rbuf, int p) {
    f16x8 hA = *(const f16x8*)(&Abuf[AB(rbuf, d_kt, d_row >> 4, (d_row & 15) + 16 * d_q0, 0)]);
    f16x8 hB = *(const f16x8*)(&Abuf[AB(rbuf, d_kt, d_row >> 4, (d_row & 15) + 16 * (d_q0 + 1), 0)]);
    float s = 0.f;
#pragma unroll
    for (int u = 0; u < 8; ++u) s += wor[u] * (float)hA[u];
#pragma unroll
    for (int u = 0; u < 8; ++u) s += wor[8 + u] * (float)hB[u];
    s += __shfl_xor(s, 1);
    s += __shfl_xor(s, 2);
    s += __shfl_xor(s, 4);
    if ((tid & 7) == 0)
      out[((size_t)(b0 + d_row)) * (PREDL * 2) + p * 2 + d_jj] = s + d_bo;
  };

  // ---------------- prediction steps 1..11 (pure h recurrence) -------------
  for (int p = 1; p < PREDL; ++p) {
    const int s = Tobs + p;
    const int rb = s & 1, wb = rb ^ 1;
    __syncthreads();
    disp_out(rb, p - 1);  // h_{p-1} lives in Abuf[rb]
    step_half(rb, wb, 0, bEr, false, 0);
    step_half(rb, wb, 1, bEr, false, 0);
  }
  __syncthreads();
  disp_out((Tobs + PREDL) & 1, PREDL - 1);  // h_11 in buf 0
}

// ---------------------------------------------------------------------------
extern "C" void kernel_launch(void* const* d_in, const int* in_sizes, int n_in,
                              void* d_out, int out_size, void* d_ws, size_t ws_size,
                              hipStream_t stream) {
  const float* obs   = (const float*)d_in[0];
  const float* nbrs  = (const float*)d_in[1];
  const float* table = (const float*)d_in[2];
  const float* W_in  = (const float*)d_in[3];
  const float* b_in  = (const float*)d_in[4];
  const float* W_sp  = (const float*)d_in[5];
  const float* b_sp  = (const float*)d_in[6];
  const float* W_ih  = (const float*)d_in[7];
  const float* W_hh  = (const float*)d_in[8];
  const float* b_ih  = (const float*)d_in[9];
  const float* b_hh  = (const float*)d_in[10];
  const float* W_out = (const float*)d_in[11];
  const float* b_out = (const float*)d_in[12];
  float* out = (float*)d_out;

  // ws layout (bytes): Wfrag f16[147456] @0 (294912) | biasO @294912 |
  //                    biasP @296960 | biasPE @299008
  char* ws = (char*)d_ws;
  f16*   Wfrag  = (f16*)(ws);
  float* biasO  = (float*)(ws + 294912);
  float* biasP  = (float*)(ws + 296960);
  float* biasPE = (float*)(ws + 299008);

  pack_all<<<512, 64, 0, stream>>>(W_ih, W_hh, W_in, W_sp, table, b_in, b_sp, b_ih, b_hh,
                                   W_out, b_out, Wfrag, biasO, biasP, biasPE);
  social_lstm_main<<<Bsz / MR, 512, 0, stream>>>(obs, nbrs, Wfrag, biasO, biasP, biasPE,
                                                 W_out, b_out, out);
}

// Round 8
// 198.598 us; speedup vs baseline: 2.0165x; 2.0165x over previous
//
#include <hip/hip_runtime.h>
#include <math.h>

typedef _Float16 f16;
typedef f16 f16x8 __attribute__((ext_vector_type(8)));
typedef float f32x4 __attribute__((ext_vector_type(4)));

#define Bsz   16384
#define Tobs  8
#define PREDL 12
#define MR    64   // batch rows per main block -> grid 256 = 1 block/CU

__device__ __forceinline__ float fast_sigm(float x) {
  float e = __builtin_amdgcn_exp2f(-1.44269504f * x);
  return __builtin_amdgcn_rcpf(1.f + e);
}
__device__ __forceinline__ float fast_tanh(float x) {
  float e = __builtin_amdgcn_exp2f(2.88539008f * x);  // e^(2x)
  return 1.f - 2.f * __builtin_amdgcn_rcpf(1.f + e);
}

// Abuf index: [buf(2)][kt(4)][mt(4)][lane(64)][j(8)] f16  (32 KB)
#define AB(buf, kt, mt, lane, j) (((((buf)*4 + (kt))*4 + (mt))*64 + (lane))*8 + (j))
// cntA index: [t(8)][mt(4)][lane(64)][j(8)] f16            (32 KB)
#define CA(t, mt, lane, j) ((((t)*4 + (mt))*64 + (lane))*8 + (j))

// Wfrag fragment slot: [ktw(9)][w(8)][nt(4)][lane(64)][j(8)] f16
// ktw 0..3: W_hh ; ktw 4: extras [cells(16)|wio(2)|0...] ; ktw 5..8: W_eff
#define WF(ktw, w, nt, lane) ((size_t)((((ktw)*8 + (w))*4 + (nt))*64 + (lane)) * 8)

// ---------------------------------------------------------------------------
// pack_all: one single-wave block per gate-row jo (512 blocks).
// cells[c] = sum_e table[c][e] * wspP[e],  wspP[e] = sum_m W_ih[jo][128+m]*W_sp[m][e]
// Emits Wfrag (W_hh | extras | W_eff = W_hh + wio (x) W_out) and the 3 biases.
// ---------------------------------------------------------------------------
__global__ __launch_bounds__(64) void pack_all(
    const float* __restrict__ W_ih, const float* __restrict__ W_hh,
    const float* __restrict__ W_in, const float* __restrict__ W_sp,
    const float* __restrict__ table,
    const float* __restrict__ b_in, const float* __restrict__ b_sp,
    const float* __restrict__ b_ih, const float* __restrict__ b_hh,
    const float* __restrict__ W_out, const float* __restrict__ b_out,
    f16* __restrict__ Wfrag, float* __restrict__ biasO,
    float* __restrict__ biasP, float* __restrict__ biasPE) {
  const int blk = blockIdx.x;            // 0..511
  const int nt = blk >> 7, w = (blk >> 4) & 7, l = blk & 15;
  const int jo = nt * 128 + w * 16 + l;  // original gate row
  const int m = threadIdx.x;             // 0..63
  __shared__ float st[256];              // hh[128] | eff[128]
  __shared__ float wspPS[32];
  __shared__ float cellsS[16];

  float a0 = W_ih[jo * 256 + m],        a1 = W_ih[jo * 256 + 64 + m];
  float s0 = W_ih[jo * 256 + 128 + m],  s1 = W_ih[jo * 256 + 192 + m];
  float hh0 = W_hh[jo * 128 + m],       hh1 = W_hh[jo * 128 + 64 + m];
  float bi0 = b_in[m], bi1 = b_in[64 + m];
  float bs0 = b_sp[m], bs1 = b_sp[64 + m];
  float wi00 = W_in[m * 2 + 0],        wi01 = W_in[m * 2 + 1];
  float wi10 = W_in[(64 + m) * 2 + 0], wi11 = W_in[(64 + m) * 2 + 1];
  float wo00 = W_out[m],       wo01 = W_out[64 + m];        // W_out[0][*]
  float wo10 = W_out[128 + m], wo11 = W_out[192 + m];       // W_out[1][*]

  auto red = [](float v) {
#pragma unroll
    for (int s = 1; s < 64; s <<= 1) v += __shfl_xor(v, s);
    return v;
  };

  // wspP[e] via butterfly reductions
#pragma unroll 4
  for (int e = 0; e < 32; ++e) {
    float wp = red(s0 * W_sp[m * 32 + e] + s1 * W_sp[(64 + m) * 32 + e]);
    if (m == e) wspPS[e] = wp;
  }
  __syncthreads();
  if (m < 16) {
    float s = 0.f;
#pragma unroll
    for (int e = 0; e < 32; ++e) s += table[m * 32 + e] * wspPS[e];
    cellsS[m] = s;
  }

  float wio0 = red(a0 * wi00 + a1 * wi10);
  float wio1 = red(a0 * wi01 + a1 * wi11);
  float dotA = red(a0 * bi0 + a1 * bi1);
  float dotS = red(s0 * bs0 + s1 * bs1);

  st[m] = hh0;
  st[64 + m] = hh1;
  st[128 + m] = hh0 + wio0 * wo00 + wio1 * wo10;
  st[192 + m] = hh1 + wio0 * wo01 + wio1 * wo11;
  __syncthreads();

  if (m < 32) {  // W_hh (which=0) and W_eff (which=1) fragment writes
    int u = m & 15, kt = u >> 2, q = u & 3;
    int which = m >> 4;
    int ktw = which ? kt + 5 : kt;
    f16x8 v;
#pragma unroll
    for (int j = 0; j < 8; ++j) v[j] = (f16)st[which * 128 + kt * 32 + q * 8 + j];
    *(f16x8*)(Wfrag + WF(ktw, w, nt, q * 16 + l)) = v;
  } else if (m < 36) {  // extras tile ktw=4, q = m-32
    int q = m - 32;
    f16x8 v;
#pragma unroll
    for (int j = 0; j < 8; ++j) {
      int kk = q * 8 + j;
      float x = (kk < 16) ? cellsS[kk] : (kk == 16 ? wio0 : (kk == 17 ? wio1 : 0.f));
      v[j] = (f16)x;
    }
    *(f16x8*)(Wfrag + WF(4, w, nt, q * 16 + l)) = v;
  } else if (m == 36) {
    int col = w * 64 + nt * 16 + l;  // permuted column index
    float base = b_ih[jo] + b_hh[jo];
    biasO[col] = base + dotA + dotS;
    float bp = base + dotA;
    biasP[col] = bp;
    biasPE[col] = bp + wio0 * b_out[0] + wio1 * b_out[1];
  }
}

// ---------------------------------------------------------------------------
// Main: 64 rows/block, 512 threads, grid 256 (1 block/CU). 20 serial steps
// per CU (vs 40 at MR=32); per-step work has 4-way mt ILP. (512,2): 256-reg
// budget, ~175 used, no spill.
// ---------------------------------------------------------------------------
__global__ __launch_bounds__(512, 2) void social_lstm_main(
    const float* __restrict__ obs, const float* __restrict__ nb,
    const f16* __restrict__ Wfrag, const float* __restrict__ biasO,
    const float* __restrict__ biasP, const float* __restrict__ biasPE,
    const float* __restrict__ W_out, const float* __restrict__ b_out,
    float* __restrict__ out) {
  __shared__ __align__(16) f16 Abuf[2 * 4 * 4 * 64 * 8];  // 32 KB
  __shared__ __align__(16) f16 cntA[8 * 4 * 64 * 8];      // 32 KB obs A-panels

  const int tid = threadIdx.x;
  const int w = tid >> 6, ln = tid & 63;
  const int q = ln >> 4, l = ln & 15;
  const int b0 = blockIdx.x * MR;

  // zero Abuf buf0 (h0 = 0) + all of cntA (channels 18..31 must be 0.0)
  for (int i = tid; i < 4096; i += 512) ((uint32_t*)Abuf)[i] = 0u;
  for (int i = tid; i < 8192; i += 512) ((uint32_t*)cntA)[i] = 0u;
  __syncthreads();

  // ---------------- fused social pooling: 8 lanes/row x 8 tracks ----------
  {
    const int r = tid >> 3;   // local row 0..63
    const int lg = tid & 7;   // lane-group within row (shfl_xor 1,2,4 stays in-row)
    const float4* orow = (const float4*)(obs + (size_t)(b0 + r) * 16);
    float4 O0 = orow[0], O1 = orow[1], O2 = orow[2], O3 = orow[3];
    float ox[8] = {O0.x, O0.z, O1.x, O1.z, O2.x, O2.z, O3.x, O3.z};
    float oy[8] = {O0.y, O0.w, O1.y, O1.w, O2.y, O2.w, O3.y, O3.w};
    unsigned long long h[8] = {0ull, 0ull, 0ull, 0ull, 0ull, 0ull, 0ull, 0ull};
#pragma unroll
    for (int half = 0; half < 2; ++half) {
      float4 T[16];
#pragma unroll
      for (int jt = 0; jt < 4; ++jt) {
        int trk = lg + 8 * (half * 4 + jt);
        const float4* tr = (const float4*)(nb + ((size_t)(b0 + r) * 64 + trk) * 16);
#pragma unroll
        for (int u = 0; u < 4; ++u) T[jt * 4 + u] = tr[u];
      }
#pragma unroll
      for (int jt = 0; jt < 4; ++jt) {
        float nx[8] = {T[jt*4+0].x, T[jt*4+0].z, T[jt*4+1].x, T[jt*4+1].z,
                       T[jt*4+2].x, T[jt*4+2].z, T[jt*4+3].x, T[jt*4+3].z};
        float ny[8] = {T[jt*4+0].y, T[jt*4+0].w, T[jt*4+1].y, T[jt*4+1].w,
                       T[jt*4+2].y, T[jt*4+2].w, T[jt*4+3].y, T[jt*4+3].w};
#pragma unroll
        for (int t = 0; t < 8; ++t) {
          float rx = nx[t] - ox[t], ry = ny[t] - oy[t];
          int ix = (int)floorf(rx + rx);
          int iy = (int)floorf(ry + ry);
          ix = min(max(ix, -2), 1);
          iy = min(max(iy, -2), 1);
          int flat = (ix + 2) * 4 + (iy + 2);  // 0..15; per-lane count <= 8
          h[t] += 1ull << (flat * 4);          // 4-bit bins (max 8, no overflow)
        }
      }
    }
    auto shx = [](unsigned long long x, int msk) {
      unsigned lo = __shfl_xor((unsigned)x, msk);
      unsigned hi = __shfl_xor((unsigned)(x >> 32), msk);
      return ((unsigned long long)hi << 32) | lo;
    };
#pragma unroll
    for (int t = 0; t < 8; ++t) {
      // split to 8-bit bins BEFORE merging (sums reach 64)
      unsigned long long e0 = h[t] & 0x0F0F0F0F0F0F0F0Full;         // even cells
      unsigned long long e1 = (h[t] >> 4) & 0x0F0F0F0F0F0F0F0Full;  // odd cells
      e0 += shx(e0, 1); e1 += shx(e1, 1);
      e0 += shx(e0, 2); e1 += shx(e1, 2);
      e0 += shx(e0, 4); e1 += shx(e1, 4);
      unsigned cA = (unsigned)(e0 >> (lg * 8)) & 0xFFu;  // cell 2*lg
      unsigned cB = (unsigned)(e1 >> (lg * 8)) & 0xFFu;  // cell 2*lg+1
      int cAc = 2 * lg, cBc = 2 * lg + 1;
      cntA[CA(t, r >> 4, (cAc >> 3) * 16 + (r & 15), cAc & 7)] = (f16)(float)cA;
      cntA[CA(t, r >> 4, (cBc >> 3) * 16 + (r & 15), cBc & 7)] = (f16)(float)cB;
    }
    // xy channels 16,17: lane lg covers t=lg for its row
    float xv = obs[(size_t)(b0 + r) * 16 + lg * 2];
    float yv = obs[(size_t)(b0 + r) * 16 + lg * 2 + 1];
    cntA[CA(lg, r >> 4, 2 * 16 + (r & 15), 0)] = (f16)xv;
    cntA[CA(lg, r >> 4, 2 * 16 + (r & 15), 1)] = (f16)yv;
  }

  // persistent W_hh B fragments + extras
  f16x8 Bh[4][4];
#pragma unroll
  for (int kt = 0; kt < 4; ++kt)
#pragma unroll
    for (int nt = 0; nt < 4; ++nt)
      Bh[kt][nt] = *(const f16x8*)(Wfrag + WF(kt, w, nt, ln));
  f16x8 Bx[4];
#pragma unroll
  for (int nt = 0; nt < 4; ++nt) Bx[nt] = *(const f16x8*)(Wfrag + WF(4, w, nt, ln));

  float creg[16];
#pragma unroll
  for (int i = 0; i < 16; ++i) creg[i] = 0.f;

  float bOr[4];
#pragma unroll
  for (int g2 = 0; g2 < 4; ++g2) bOr[g2] = biasO[w * 64 + g2 * 16 + l];

  const int hc = w * 16 + l;
  const int aw_kt = hc >> 5, aw_quad = (hc >> 3) & 3, aw_j = l & 7;

  // One mt-quarter of a step: acc[4] (16 regs), MFMA chain then epilogue.
  auto step_half = [&](int rb, int wb, int mt, const float* bq, bool ex, int t) {
    f32x4 a[4];
#pragma unroll
    for (int nt = 0; nt < 4; ++nt) a[nt] = (f32x4){bq[nt], bq[nt], bq[nt], bq[nt]};
    if (ex) {
      f16x8 Ax = *(const f16x8*)(&cntA[CA(t, mt, ln, 0)]);
#pragma unroll
      for (int nt = 0; nt < 4; ++nt)
        a[nt] = __builtin_amdgcn_mfma_f32_16x16x32_f16(Ax, Bx[nt], a[nt], 0, 0, 0);
    }
#pragma unroll
    for (int kt = 0; kt < 4; ++kt) {
      f16x8 Af = *(const f16x8*)(&Abuf[AB(rb, kt, mt, ln, 0)]);
#pragma unroll
      for (int nt = 0; nt < 4; ++nt)
        a[nt] = __builtin_amdgcn_mfma_f32_16x16x32_f16(Af, Bh[kt][nt], a[nt], 0, 0, 0);
    }
#pragma unroll
    for (int reg = 0; reg < 4; ++reg) {
      float p0 = a[0][reg], p1 = a[1][reg], p2 = a[2][reg], p3 = a[3][reg];
      float iv = fast_sigm(p0), fv = fast_sigm(p1);
      float gv = fast_tanh(p2), ov = fast_sigm(p3);
      int ci = mt * 4 + reg;
      float c2 = fv * creg[ci] + iv * gv;
      creg[ci] = c2;
      float hv = ov * fast_tanh(c2);
      Abuf[AB(wb, aw_kt, mt, (q * 4 + reg) + 16 * aw_quad, aw_j)] = (f16)hv;
    }
  };

  // ---------------- observation phase ----------------
#pragma unroll
  for (int t = 0; t < Tobs; ++t) {
    const int rb = t & 1, wb = rb ^ 1;
    __syncthreads();
#pragma unroll
    for (int mt = 0; mt < 4; ++mt) step_half(rb, wb, mt, bOr, true, t);
  }

  // ---------------- prediction step 0 (prev disp = 0, plain W_hh) ----------
  {
    float bPr[4];
#pragma unroll
    for (int g2 = 0; g2 < 4; ++g2) bPr[g2] = biasP[w * 64 + g2 * 16 + l];
    const int rb = Tobs & 1, wb = rb ^ 1;  // rb=0, wb=1
    __syncthreads();
#pragma unroll
    for (int mt = 0; mt < 4; ++mt) step_half(rb, wb, mt, bPr, false, 0);
  }

  // swap to W_eff + biasPE; preload W_out dot registers for disp output
#pragma unroll
  for (int kt = 0; kt < 4; ++kt)
#pragma unroll
    for (int nt = 0; nt < 4; ++nt)
      Bh[kt][nt] = *(const f16x8*)(Wfrag + WF(kt + 5, w, nt, ln));
  float bEr[4];
#pragma unroll
  for (int g2 = 0; g2 < 4; ++g2) bEr[g2] = biasPE[w * 64 + g2 * 16 + l];

  // disp: 4 threads per (row, jj) dot; thread covers 32 h-cols (= one kt seg)
  const int d_oi = tid >> 2, d_seg = tid & 3;
  const int d_row = d_oi >> 1, d_jj = d_oi & 1;
  float wor[32];
  {
    const float4* wp = (const float4*)(W_out + d_jj * 128 + d_seg * 32);
#pragma unroll
    for (int u = 0; u < 8; ++u) {
      float4 v = wp[u];
      wor[4 * u] = v.x; wor[4 * u + 1] = v.y; wor[4 * u + 2] = v.z; wor[4 * u + 3] = v.w;
    }
  }
  const float d_bo = b_out[d_jj];

  auto disp_out = [&](int rbuf, int p) {
    float s = 0.f;
#pragma unroll
    for (int quad = 0; quad < 4; ++quad) {
      f16x8 h8 = *(const f16x8*)(
          &Abuf[AB(rbuf, d_seg, d_row >> 4, (d_row & 15) + 16 * quad, 0)]);
#pragma unroll
      for (int u = 0; u < 8; ++u) s += wor[quad * 8 + u] * (float)h8[u];
    }
    s += __shfl_xor(s, 1);
    s += __shfl_xor(s, 2);
    if ((tid & 3) == 0)
      out[((size_t)(b0 + d_row)) * (PREDL * 2) + p * 2 + d_jj] = s + d_bo;
  };

  // ---------------- prediction steps 1..11 (pure h recurrence) -------------
  for (int p = 1; p < PREDL; ++p) {
    const int s = Tobs + p;
    const int rb = s & 1, wb = rb ^ 1;
    __syncthreads();
    disp_out(rb, p - 1);  // h_{p-1} lives in Abuf[rb]
#pragma unroll
    for (int mt = 0; mt < 4; ++mt) step_half(rb, wb, mt, bEr, false, 0);
  }
  __syncthreads();
  disp_out((Tobs + PREDL) & 1, PREDL - 1);  // h_11 in buf 0
}

// ---------------------------------------------------------------------------
extern "C" void kernel_launch(void* const* d_in, const int* in_sizes, int n_in,
                              void* d_out, int out_size, void* d_ws, size_t ws_size,
                              hipStream_t stream) {
  const float* obs   = (const float*)d_in[0];
  const float* nbrs  = (const float*)d_in[1];
  const float* table = (const float*)d_in[2];
  const float* W_in  = (const float*)d_in[3];
  const float* b_in  = (const float*)d_in[4];
  const float* W_sp  = (const float*)d_in[5];
  const float* b_sp  = (const float*)d_in[6];
  const float* W_ih  = (const float*)d_in[7];
  const float* W_hh  = (const float*)d_in[8];
  const float* b_ih  = (const float*)d_in[9];
  const float* b_hh  = (const float*)d_in[10];
  const float* W_out = (const float*)d_in[11];
  const float* b_out = (const float*)d_in[12];
  float* out = (float*)d_out;

  // ws layout (bytes): Wfrag f16[147456] @0 (294912) | biasO @294912 |
  //                    biasP @296960 | biasPE @299008
  char* ws = (char*)d_ws;
  f16*   Wfrag  = (f16*)(ws);
  float* biasO  = (float*)(ws + 294912);
  float* biasP  = (float*)(ws + 296960);
  float* biasPE = (float*)(ws + 299008);

  pack_all<<<512, 64, 0, stream>>>(W_ih, W_hh, W_in, W_sp, table, b_in, b_sp, b_ih, b_hh,
                                   W_out, b_out, Wfrag, biasO, biasP, biasPE);
  social_lstm_main<<<Bsz / MR, 512, 0, stream>>>(obs, nbrs, Wfrag, biasO, biasP, biasPE,
                                                 W_out, b_out, out);
}